// Round 27
// baseline (487.715 us; speedup 1.0000x reference)
//
#include <hip/hip_runtime.h>
#include <stdint.h>

#define BATCH 8
#define NPTS  16384
#define BN    (BATCH * NPTS)
#define NT    512                 // 32-point tiles per batch
#define NTH   256                 // tiles per kh half
#define QPB   256                 // queries per block
#define MARGIN 3.0e-3f            // > 2*delta_worst (2.6e-3), deterministic bound

typedef float f32x16 __attribute__((ext_vector_type(16)));
typedef short s16x8  __attribute__((ext_vector_type(8)));

__device__ __forceinline__ uint16_t bfr(float x) {
    uint32_t u = __float_as_uint(x);
    return (uint16_t)((u + 0x7FFFu + ((u >> 16) & 1u)) >> 16);
}
__device__ __forceinline__ float bff(uint16_t s) {
    return __uint_as_float(((uint32_t)s) << 16);
}
__device__ __forceinline__ void split2(float v, uint16_t* a, uint16_t* b) {
    *a = bfr(v); *b = bfr(v - bff(*a));
}
__device__ __forceinline__ uint32_t pk2(uint16_t lo, uint16_t hi) {
    return (uint32_t)lo | ((uint32_t)hi << 16);
}
__device__ __forceinline__ uint32_t key32(float d) {
    uint32_t b = __float_as_uint(d);
    return (b & 0x80000000u) ? ~b : (b | 0x80000000u);
}
__device__ __forceinline__ float dec32(uint32_t k) {
    return __uint_as_float((k & 0x80000000u) ? (k ^ 0x80000000u) : ~k);
}

#define F16(M_) M_(0) M_(1) M_(2) M_(3) M_(4) M_(5) M_(6) M_(7) \
                M_(8) M_(9) M_(10) M_(11) M_(12) M_(13) M_(14) M_(15)

#define MIN3(a, b, c) fminf(fminf((a), (b)), (c))

__device__ __forceinline__ float fold16(const f32x16 a) {
    const float u0 = MIN3(a[0],  a[1],  a[2]);
    const float u1 = MIN3(a[3],  a[4],  a[5]);
    const float u2 = MIN3(a[6],  a[7],  a[8]);
    const float u3 = MIN3(a[9],  a[10], a[11]);
    const float u4 = MIN3(a[12], a[13], a[14]);
    const float v0 = MIN3(u0, u1, a[15]);
    const float v1 = MIN3(u2, u3, u4);
    return fminf(v0, v1);
}

// ---- enc2: [b][tile][64 uint4] lane-linear A-fragments + y4 table ----
__global__ __launch_bounds__(256) void enc_kernel(
    const float* __restrict__ Y, uint4* __restrict__ enc2,
    float4* __restrict__ y4)
{
#pragma clang fp contract(off)
    const int g = blockIdx.x * 256 + threadIdx.x;     // 0..BN-1
    const int b = g >> 14, p = g & (NPTS - 1);
    const float y0 = Y[(size_t)g * 3 + 0];
    const float y1 = Y[(size_t)g * 3 + 1];
    const float y2 = Y[(size_t)g * 3 + 2];
    const float ys = (y0 * y0 + y1 * y1) + y2 * y2;   // np order
    uint16_t Ya, Yb; split2(ys, &Ya, &Yb);
    uint16_t H0, M0; split2(-2.0f * y0, &H0, &M0);
    uint16_t H1, M1; split2(-2.0f * y1, &H1, &M1);
    uint16_t H2, M2; split2(-2.0f * y2, &H2, &M2);
    const uint16_t ONE = 0x3F80;
    const int tile = p >> 5, col = p & 31;
    const size_t base = ((size_t)b * NT + tile) * 64;
    enc2[base + col]      = make_uint4(pk2(ONE, ONE), pk2(Ya, Yb), pk2(H0, M0), pk2(H0, M0));
    enc2[base + 32 + col] = make_uint4(pk2(H1, M1), pk2(H1, M1), pk2(H2, M2), pk2(H2, M2));
    y4[g] = make_float4(y0, y1, y2, ys);
}

#define MKQFR(dst, qq) { \
        const float* xp = Xp + (size_t)(qq) * 3; \
        const float x0 = xp[0], x1 = xp[1], x2 = xp[2]; \
        const float xs = (x0 * x0 + x1 * x1) + x2 * x2; \
        uint16_t Xa, Xb; split2(xs, &Xa, &Xb); \
        uint16_t h0, m0; split2(x0, &h0, &m0); \
        uint16_t h1, m1; split2(x1, &h1, &m1); \
        uint16_t h2, m2; split2(x2, &h2, &m2); \
        const uint16_t ONE = 0x3F80; \
        if (hi == 0) { \
            dst[0]=(short)Xa; dst[1]=(short)Xb; dst[2]=(short)ONE; dst[3]=(short)ONE; \
            dst[4]=(short)h0; dst[5]=(short)h0; dst[6]=(short)m0;  dst[7]=(short)m0; \
        } else { \
            dst[0]=(short)h1; dst[1]=(short)h1; dst[2]=(short)m1;  dst[3]=(short)m1; \
            dst[4]=(short)h2; dst[5]=(short)h2; dst[6]=(short)m2;  dst[7]=(short)m2; \
        } }

// fused both-dir decode (bijective; proven R19-R23): 2048 blocks
#define SWEEP_DECODE() \
    const int tid = threadIdx.x; \
    const int l   = tid & 63; \
    const int wv  = tid >> 6; \
    const int col = l & 31; \
    const int hi  = l >> 5; \
    int dir, batch, kh, xblk; \
    { const int g = blockIdx.x; \
      const int s = 2 * (g & 7) + ((g >> 3) & 1); \
      dir = s >> 3; batch = s & 7; kh = (g >> 4) & 1; xblk = g >> 5; } \
    const float* Xp = dir ? xyz2 : xyz1; \
    const uint4* pb = (dir ? enc2B : enc2A) + \
                      ((size_t)batch * NT + (size_t)kh * NTH) * 64; \
    const int qbase = batch * NPTS + xblk * QPB + wv * 64;

// ===== sweep1: streaming per-query approx min -> mkey =====
__global__ __launch_bounds__(256, 4) void nn_sweep1(
    const float* __restrict__ xyz1, const float* __restrict__ xyz2,
    const uint4* __restrict__ enc2A, const uint4* __restrict__ enc2B,
    uint32_t* __restrict__ mkey)
{
#pragma clang fp contract(off)
    SWEEP_DECODE()

    const f32x16 zf = {0.f,0.f,0.f,0.f,0.f,0.f,0.f,0.f,
                       0.f,0.f,0.f,0.f,0.f,0.f,0.f,0.f};

    s16x8 qfr0, qfr1;
    MKQFR(qfr0, qbase + col)
    MKQFR(qfr1, qbase + 32 + col)

    float run0 = __builtin_inff(), run1 = __builtin_inff();

    uint4 n0 = pb[0 * 64 + l], n1 = pb[1 * 64 + l];
    uint4 n2 = pb[2 * 64 + l], n3 = pb[3 * 64 + l];
    for (int t = 0; t < NTH; t += 4) {
        const uint4 c0 = n0, c1 = n1, c2 = n2, c3 = n3;
        const uint4* nb = pb + (size_t)(t + 4) * 64;   // tail reads stay in valid ws
        n0 = nb[0 * 64 + l]; n1 = nb[1 * 64 + l];
        n2 = nb[2 * 64 + l]; n3 = nb[3 * 64 + l];
#define S1T(cq) { \
        const s16x8 pA = __builtin_bit_cast(s16x8, cq); \
        const f32x16 a0 = __builtin_amdgcn_mfma_f32_32x32x16_bf16(pA, qfr0, zf, 0, 0, 0); \
        run0 = fminf(run0, fold16(a0)); \
        const f32x16 a1 = __builtin_amdgcn_mfma_f32_32x32x16_bf16(pA, qfr1, zf, 0, 0, 0); \
        run1 = fminf(run1, fold16(a1)); }
        S1T(c0) S1T(c1) S1T(c2) S1T(c3)
#undef S1T
    }
    run0 = fminf(run0, __shfl_xor(run0, 32, 64));
    run1 = fminf(run1, __shfl_xor(run1, 32, 64));
    if (hi == 0) {
        uint32_t* mp = mkey + (size_t)dir * BN;
        atomicMin(&mp[qbase + col],      key32(run0));
        atomicMin(&mp[qbase + 32 + col], key32(run1));
    }
}

// ===== sweep2: streaming + mask-loop exact walk into LDS keys =====
__global__ __launch_bounds__(256, 4) void nn_sweep2(
    const float* __restrict__ xyz1, const float* __restrict__ xyz2,
    const uint4* __restrict__ enc2A, const uint4* __restrict__ enc2B,
    const float4* __restrict__ y4A, const float4* __restrict__ y4B,
    const uint32_t* __restrict__ mkey, unsigned long long* __restrict__ gkeys)
{
#pragma clang fp contract(off)
    __shared__ unsigned long long keys[QPB];           // 2 KB
    SWEEP_DECODE()

    const float4* Y4 = (dir ? y4B : y4A) + (size_t)batch * NPTS;

    keys[tid] = ~0ull;

    const f32x16 zf = {0.f,0.f,0.f,0.f,0.f,0.f,0.f,0.f,
                       0.f,0.f,0.f,0.f,0.f,0.f,0.f,0.f};

    // A-side (point) row calibration -> two u64s (branchless runtime select,
    // avoids runtime-indexed register array -> scratch; rule #20)
    uint64_t rplo = 0, rphi = 0;
    {
        s16x8 pa = {0,0,0,0,0,0,0,0}, pbq = {0,0,0,0,0,0,0,0};
        if (hi == 0) { pa[0] = (short)bfr((float)col); pbq[0] = (short)0x3F80; }
        const f32x16 rowp = __builtin_amdgcn_mfma_f32_32x32x16_bf16(pa, pbq, zf, 0, 0, 0);
#define PR(i) { const uint64_t e_ = (uint64_t)((int)rowp[i] & 0xFF); \
                if ((i) < 8) rplo |= e_ << ((i) * 8); \
                else         rphi |= e_ << (((i) - 8) * 8); }
        F16(PR)
#undef PR
    }

    s16x8 qfr0, qfr1;
    float qa0, qa1, qa2, qas, qb0, qb1, qb2, qbs;
    {
        const float* xp = Xp + (size_t)(qbase + col) * 3;
        qa0 = xp[0]; qa1 = xp[1]; qa2 = xp[2];
        qas = (qa0 * qa0 + qa1 * qa1) + qa2 * qa2;
    }
    {
        const float* xp = Xp + (size_t)(qbase + 32 + col) * 3;
        qb0 = xp[0]; qb1 = xp[1]; qb2 = xp[2];
        qbs = (qb0 * qb0 + qb1 * qb1) + qb2 * qb2;
    }
    MKQFR(qfr0, qbase + col)
    MKQFR(qfr1, qbase + 32 + col)

    const uint32_t* mp = mkey + (size_t)dir * BN;
    const float thr0 = dec32(mp[qbase + col]) + MARGIN;
    const float thr1 = dec32(mp[qbase + 32 + col]) + MARGIN;

    __syncthreads();                                   // keys[] initialized

    // mask-loop walk: build 16-bit candidate mask, iterate set bits only.
#define WALK(accv, jb, foff, thr, qx0, qx1, qx2, qxs) { \
        uint32_t msk = 0; \
        _Pragma("unroll") \
        for (int i_ = 0; i_ < 16; ++i_) \
            msk |= ((accv)[i_] <= (thr)) ? (1u << i_) : 0u; \
        while (msk) { \
            const int r_ = __builtin_ctz(msk); \
            msk &= msk - 1; \
            const uint64_t rp_ = (r_ & 8) ? rphi : rplo; \
            const int jc = (jb) + (int)((rp_ >> ((r_ & 7) * 8)) & 0xFF); \
            const float4 yv = Y4[jc]; \
            const float dd = ((qxs) - 2.0f * (((qx0) * yv.x + (qx1) * yv.y) + (qx2) * yv.z)) + yv.w; \
            atomicMin(&keys[wv * 64 + (foff) + col], \
                      ((unsigned long long)key32(dd) << 32) | (uint32_t)jc); \
        } }

    uint4 n0 = pb[0 * 64 + l], n1 = pb[1 * 64 + l];
    for (int t = 0; t < NTH; t += 2) {
        const uint4 c0 = n0, c1 = n1;
        const uint4* nb = pb + (size_t)(t + 2) * 64;   // tail reads stay in valid ws
        n0 = nb[0 * 64 + l]; n1 = nb[1 * 64 + l];
#define S2T(cq, j) { \
        const s16x8 pA = __builtin_bit_cast(s16x8, cq); \
        const int jb = (kh * NTH + t + (j)) * 32; \
        const f32x16 a0 = __builtin_amdgcn_mfma_f32_32x32x16_bf16(pA, qfr0, zf, 0, 0, 0); \
        WALK(a0, jb, 0, thr0, qa0, qa1, qa2, qas) \
        const f32x16 a1 = __builtin_amdgcn_mfma_f32_32x32x16_bf16(pA, qfr1, zf, 0, 0, 0); \
        WALK(a1, jb, 32, thr1, qb0, qb1, qb2, qbs) }
        S2T(c0, 0) S2T(c1, 1)
#undef S2T
    }
#undef WALK

    __syncthreads();
    {
        const unsigned long long m = keys[tid];
        atomicMin(&gkeys[(size_t)dir * BN + batch * NPTS + xblk * QPB + tid], m);
    }
}

// ---- final: gkeys (both dirs) -> (dist, idx) ----
__global__ __launch_bounds__(256) void writeout_k(
    const unsigned long long* __restrict__ gkeys, float* __restrict__ out)
{
    const size_t i = (size_t)blockIdx.x * 256 + threadIdx.x;   // 0..2*BN-1
    const unsigned long long m = gkeys[i];
    const int dir = (int)(i / BN);
    const size_t q = i - (size_t)dir * BN;
    out[(size_t)dir * BN + q]       = dec32((uint32_t)(m >> 32));
    out[(size_t)(2 + dir) * BN + q] = (float)(uint32_t)(m & 0xFFFFFFFFu);
}

extern "C" void kernel_launch(void* const* d_in, const int* in_sizes, int n_in,
                              void* d_out, int out_size, void* d_ws, size_t ws_size,
                              hipStream_t stream) {
    const float* xyz1 = (const float*)d_in[0];
    const float* xyz2 = (const float*)d_in[1];
    float* out = (float*)d_out;

    // ws: enc2A 4M | enc2B 4M | y4A 2M | y4B 2M | mkey 1M | gkeys 2M = 15 MiB
    char* base = (char*)d_ws;
    uint4*    enc2A = (uint4*)base;
    uint4*    enc2B = (uint4*)(base + (size_t)4 * 1024 * 1024);
    float4*   y4A   = (float4*)(base + (size_t)8 * 1024 * 1024);
    float4*   y4B   = (float4*)(base + (size_t)10 * 1024 * 1024);
    uint32_t* mkey  = (uint32_t*)(base + (size_t)12 * 1024 * 1024);
    unsigned long long* gkeys =
        (unsigned long long*)(base + (size_t)13 * 1024 * 1024);

    enc_kernel<<<BN / 256, 256, 0, stream>>>(xyz2, enc2A, y4A);   // dir0 points
    enc_kernel<<<BN / 256, 256, 0, stream>>>(xyz1, enc2B, y4B);   // dir1 points
    hipMemsetAsync(mkey, 0xFF, (size_t)3 * 1024 * 1024, stream);  // mkey + gkeys

    nn_sweep1<<<2048, 256, 0, stream>>>(xyz1, xyz2, enc2A, enc2B, mkey);
    nn_sweep2<<<2048, 256, 0, stream>>>(xyz1, xyz2, enc2A, enc2B,
                                        y4A, y4B, mkey, gkeys);
    writeout_k<<<(2 * BN) / 256, 256, 0, stream>>>(gkeys, out);
}